// Round 1
// baseline (1383.517 us; speedup 1.0000x reference)
//
#include <hip/hip_runtime.h>

#define BB 4
#define NN 256
#define DD 256
#define HH 256

// Kernel 1: S[b,i,h] = sum_d X[b,i,d]*Wa[d,h];  T[b,j,h] = sum_d X[b,j,d]*Wb[d,h]
__global__ __launch_bounds__(256) void precomp_st(const float* __restrict__ X,
                                                  const float* __restrict__ W1,
                                                  float* __restrict__ S,
                                                  float* __restrict__ T) {
  const int bi = blockIdx.x;       // b*N + row
  const int h  = threadIdx.x;
  __shared__ float xr[DD];
  xr[h] = X[(size_t)bi * DD + h];
  __syncthreads();
  const float* __restrict__ Wa = W1;
  const float* __restrict__ Wb = W1 + (size_t)DD * HH;
  float sa = 0.f, sb = 0.f;
#pragma unroll 4
  for (int d = 0; d < DD; ++d) {
    const float x = xr[d];
    sa = fmaf(x, Wa[(size_t)d * HH + h], sa);
    sb = fmaf(x, Wb[(size_t)d * HH + h], sb);
  }
  S[(size_t)bi * HH + h] = sa;
  T[(size_t)bi * HH + h] = sb;
}

// Kernel 2: one block per (b,i); thread j computes score(b,i,j) then block softmax.
__global__ __launch_bounds__(256, 4) void score_kernel(const float* __restrict__ X,
                                                       const float* __restrict__ W1,
                                                       const float* __restrict__ b1,
                                                       const float* __restrict__ W2,
                                                       const float* __restrict__ b2,
                                                       const float* __restrict__ S,
                                                       const float* __restrict__ T,
                                                       float* __restrict__ out) {
  const int bi = blockIdx.x;        // b*N + i
  const int b  = bi >> 8;
  const int i  = bi & 255;
  const int j  = threadIdx.x;

  __shared__ __align__(16) float xi[DD];
  __shared__ __align__(16) float pre[HH];
  __shared__ float red[NN];

  xi[j]  = X[(size_t)bi * DD + j];
  pre[j] = S[(size_t)bi * HH + j] + b1[j];
  __syncthreads();

  const float* __restrict__ xj = X + (size_t)(b * NN + j) * DD;
  const float* __restrict__ Wc = W1 + (size_t)2 * DD * HH;
  const float* __restrict__ Wd = W1 + (size_t)3 * DD * HH;
  const float* __restrict__ Tr = T + (size_t)(b * NN + j) * HH;

  float score = 0.f;

  for (int h0 = 0; h0 < HH; h0 += 16) {
    float acc[16];
#pragma unroll
    for (int q = 0; q < 4; ++q) {
      const float4 t4 = *reinterpret_cast<const float4*>(Tr + h0 + 4 * q);
      acc[4 * q + 0] = pre[h0 + 4 * q + 0] + t4.x;
      acc[4 * q + 1] = pre[h0 + 4 * q + 1] + t4.y;
      acc[4 * q + 2] = pre[h0 + 4 * q + 2] + t4.z;
      acc[4 * q + 3] = pre[h0 + 4 * q + 3] + t4.w;
    }
    for (int d0 = 0; d0 < DD; d0 += 4) {
      const float4 xj4 = *reinterpret_cast<const float4*>(xj + d0);
      const float4 xi4 = *reinterpret_cast<const float4*>(xi + d0);
      const float xiv[4] = {xi4.x, xi4.y, xi4.z, xi4.w};
      const float xjv[4] = {xj4.x, xj4.y, xj4.z, xj4.w};
#pragma unroll
      for (int dd = 0; dd < 4; ++dd) {
        const float a = __builtin_fabsf(xiv[dd] - xjv[dd]);
        const float p = xiv[dd] * xjv[dd];
        // uniform addresses (d0,dd,h0 are wave-uniform) -> scalar s_load path
        const float* __restrict__ wc = Wc + (size_t)(d0 + dd) * HH + h0;
        const float* __restrict__ wd = Wd + (size_t)(d0 + dd) * HH + h0;
#pragma unroll
        for (int k = 0; k < 16; ++k) {
          acc[k] += a * wc[k] + p * wd[k];
        }
      }
    }
#pragma unroll
    for (int k = 0; k < 16; ++k) {
      const float hv = acc[k];
      const float sv = hv / (1.f + __expf(-hv));   // silu
      score = fmaf(sv, W2[h0 + k], score);
    }
  }

  score += b2[0];
  if (j == i) score = -1.0e9f;

  // block-local softmax over the 256 scores
  red[j] = score;
  __syncthreads();
#pragma unroll
  for (int s = 128; s > 0; s >>= 1) {
    if (j < s) red[j] = fmaxf(red[j], red[j + s]);
    __syncthreads();
  }
  const float m = red[0];
  __syncthreads();
  const float e = __expf(score - m);
  red[j] = e;
  __syncthreads();
#pragma unroll
  for (int s = 128; s > 0; s >>= 1) {
    if (j < s) red[j] += red[j + s];
    __syncthreads();
  }
  out[(size_t)bi * NN + j] = e / red[0];
}

extern "C" void kernel_launch(void* const* d_in, const int* in_sizes, int n_in,
                              void* d_out, int out_size, void* d_ws, size_t ws_size,
                              hipStream_t stream) {
  const float* X  = (const float*)d_in[0];
  const float* W1 = (const float*)d_in[1];
  const float* b1 = (const float*)d_in[2];
  const float* W2 = (const float*)d_in[3];
  const float* b2 = (const float*)d_in[4];
  float* out = (float*)d_out;

  float* S = (float*)d_ws;                     // B*N*H floats
  float* T = S + (size_t)BB * NN * HH;         // B*N*H floats  (2 MB total)

  precomp_st<<<BB * NN, 256, 0, stream>>>(X, W1, S, T);
  score_kernel<<<BB * NN, 256, 0, stream>>>(X, W1, b1, W2, b2, S, T, out);
}

// Round 3
// 307.356 us; speedup vs baseline: 4.5013x; 4.5013x over previous
//
#include <hip/hip_runtime.h>

#define BB 4
#define NN 256
#define DD 256
#define HH 256

typedef _Float16 half8 __attribute__((ext_vector_type(8)));
typedef __fp16   fp16x2 __attribute__((ext_vector_type(2)));
typedef float floatx4 __attribute__((ext_vector_type(4)));

// ---------- kernel 0: Wc/Wd (fp32) -> interleaved f16, chunk-major ----------
// Wf16 logical layout: [c][h][kkloc], c in [0,8), kkloc in [0,64).
// Global k index kk = c*64 + kkloc = 2*d + t; t=0 -> Wc[d][h], t=1 -> Wd[d][h].
__global__ __launch_bounds__(256) void wcvt_kernel(const float* __restrict__ W1,
                                                   _Float16* __restrict__ Wf16) {
  const int d = blockIdx.x;    // 0..255
  const int h = threadIdx.x;   // 0..255
  const float wc = W1[(size_t)(2 * DD + d) * HH + h];
  const float wd = W1[(size_t)(3 * DD + d) * HH + h];
  const int c  = d >> 5;
  const int dd = d & 31;
  _Float16* p = Wf16 + ((size_t)c * HH * 64 + (size_t)h * 64 + 2 * dd);
  p[0] = (_Float16)wc;   // RTN
  p[1] = (_Float16)wd;
}

// ---------- kernel 1: S[row,h] = X[row,:]*Wa, T[row,h] = X[row,:]*Wb ----------
// 8 rows per block so W traffic is amortized 8x.
#define RPB 8
__global__ __launch_bounds__(256) void precomp_st(const float* __restrict__ X,
                                                  const float* __restrict__ W1,
                                                  float* __restrict__ S,
                                                  float* __restrict__ T) {
  const int h    = threadIdx.x;
  const int row0 = blockIdx.x * RPB;       // global row = b*N + i
  __shared__ float xr[RPB][DD];
#pragma unroll
  for (int r = 0; r < RPB; ++r) xr[r][h] = X[(size_t)(row0 + r) * DD + h];
  __syncthreads();
  const float* __restrict__ Wa = W1;
  const float* __restrict__ Wb = W1 + (size_t)DD * HH;
  float sa[RPB], sb[RPB];
#pragma unroll
  for (int r = 0; r < RPB; ++r) { sa[r] = 0.f; sb[r] = 0.f; }
  for (int d = 0; d < DD; ++d) {
    const float wa = Wa[(size_t)d * HH + h];
    const float wb = Wb[(size_t)d * HH + h];
#pragma unroll
    for (int r = 0; r < RPB; ++r) {
      const float x = xr[r][d];            // LDS broadcast (free)
      sa[r] = fmaf(x, wa, sa[r]);
      sb[r] = fmaf(x, wb, sb[r]);
    }
  }
#pragma unroll
  for (int r = 0; r < RPB; ++r) {
    S[(size_t)(row0 + r) * HH + h] = sa[r];
    T[(size_t)(row0 + r) * HH + h] = sb[r];
  }
}

// ---------- kernel 2: MFMA pair-scores + softmax, one block per (b,i) ----------
// Per block: C[j,h] = sum_k A[j,k]*B[k,h], K=512 interleaved (diff,prod);
// h_full = C + S[i,h] + T[j,h] + b1; score[j] = sum_h silu(h_full)*w2[h]; softmax_j.
// 8 waves: wave (wr,wc) wr=0..3, wc=0..1 owns j-tiles wr*4+[0,4), h-tiles wc*8+[0,8).
__global__ __launch_bounds__(512, 2) void score_mfma(
    const float* __restrict__ X,  const float* __restrict__ b1,
    const float* __restrict__ W2, const float* __restrict__ b2,
    const float* __restrict__ S,  const float* __restrict__ T,
    const _Float16* __restrict__ Wf16, float* __restrict__ out) {

  const int bi   = blockIdx.x;
  const int b    = bi >> 8;
  const int i    = bi & 255;
  const int t    = threadIdx.x;
  const int lane = t & 63;
  const int wid  = t >> 6;
  const int wr   = wid >> 1;      // 0..3
  const int wc   = wid & 1;       // 0..1
  const int q    = lane >> 4;     // 0..3
  const int cc   = lane & 15;     // 0..15

  __shared__ __align__(16) float    xi_s[DD];
  __shared__ __align__(16) _Float16 B_s[HH][72];   // padded: 144B rows, 16B aligned
  __shared__ float pre_s[HH];
  __shared__ float w2_s[HH];
  __shared__ float sc_s[2 * NN];
  __shared__ float red_s[NN];

  if (t < 256) {
    xi_s[t]  = X[(size_t)bi * DD + t];
    pre_s[t] = S[(size_t)bi * HH + t] + b1[t];
    w2_s[t]  = W2[t];
  }

  const float* __restrict__ Xb = X + (size_t)b * NN * DD;
  const float* __restrict__ Tb = T + (size_t)b * NN * HH;

  floatx4 acc[4][8];
#pragma unroll
  for (int jj = 0; jj < 4; ++jj)
#pragma unroll
    for (int hh = 0; hh < 8; ++hh) acc[jj][hh] = (floatx4)0.f;

  // B-chunk staging: thread copies 64B of row hrow, half hhalf.
  const int hrow  = t >> 1;
  const int hhalf = t & 1;
  const uint4* __restrict__ wsrc = (const uint4*)Wf16;  // chunk c at uint4 idx c*2048
  const int bidx = hrow * 8 + hhalf * 4;
  uint4 bpre[4];
#pragma unroll
  for (int u = 0; u < 4; ++u) bpre[u] = wsrc[bidx + u];

  for (int ch = 0; ch < 8; ++ch) {
    __syncthreads();                       // previous chunk's reads done
    uint4* bdst = (uint4*)&B_s[hrow][hhalf * 32];
#pragma unroll
    for (int u = 0; u < 4; ++u) bdst[u] = bpre[u];
    if (ch < 7) {
#pragma unroll
      for (int u = 0; u < 4; ++u) bpre[u] = wsrc[(ch + 1) * 2048 + bidx + u];
    }
    __syncthreads();                       // B_s ready

#pragma unroll
    for (int ksl = 0; ksl < 2; ++ksl) {
      const int ks    = ch * 2 + ksl;      // K-step 0..15 (K=32 each)
      const int dbase = ks * 16 + q * 4;   // this lane's 4 d's
      const float4 xiv = *(const float4*)&xi_s[dbase];   // broadcast over cc
      half8 afrag[4];
#pragma unroll
      for (int jj = 0; jj < 4; ++jj) {
        const int j = (wr * 4 + jj) * 16 + cc;           // A row m = lane&15
        const float4 xj = *(const float4*)(Xb + (size_t)j * DD + dbase);
        union { half8 v; fp16x2 h2[4]; } af;
        af.h2[0] = __builtin_amdgcn_cvt_pkrtz(fabsf(xiv.x - xj.x), xiv.x * xj.x);
        af.h2[1] = __builtin_amdgcn_cvt_pkrtz(fabsf(xiv.y - xj.y), xiv.y * xj.y);
        af.h2[2] = __builtin_amdgcn_cvt_pkrtz(fabsf(xiv.z - xj.z), xiv.z * xj.z);
        af.h2[3] = __builtin_amdgcn_cvt_pkrtz(fabsf(xiv.w - xj.w), xiv.w * xj.w);
        afrag[jj] = af.v;
      }
#pragma unroll
      for (int hh = 0; hh < 8; ++hh) {
        const int hr = (wc * 8 + hh) * 16 + cc;          // B row n = lane&15
        const half8 bfrag = *(const half8*)&B_s[hr][ksl * 32 + q * 8];
#pragma unroll
        for (int jj = 0; jj < 4; ++jj)
          acc[jj][hh] = __builtin_amdgcn_mfma_f32_16x16x32_f16(afrag[jj], bfrag,
                                                               acc[jj][hh], 0, 0, 0);
      }
    }
  }

  // ---- epilogue: add S/T/b1, silu, dot w2 ----
  float psum[4][4];
#pragma unroll
  for (int jj = 0; jj < 4; ++jj)
#pragma unroll
    for (int r = 0; r < 4; ++r) psum[jj][r] = 0.f;

#pragma unroll
  for (int hh = 0; hh < 8; ++hh) {
    const int h = (wc * 8 + hh) * 16 + cc;
    const float w2v = w2_s[h];
    const float pv  = pre_s[h];
#pragma unroll
    for (int jj = 0; jj < 4; ++jj) {
#pragma unroll
      for (int r = 0; r < 4; ++r) {
        const int j = (wr * 4 + jj) * 16 + q * 4 + r;    // C/D row = quad*4+reg
        const float tv = Tb[(size_t)j * HH + h];
        const float hv = acc[jj][hh][r] + pv + tv;
        const float sv = hv / (1.f + __expf(-hv));       // silu
        psum[jj][r] = fmaf(sv, w2v, psum[jj][r]);
      }
    }
  }

  // reduce over the 16 h-columns (lane bits 0..3)
#pragma unroll
  for (int jj = 0; jj < 4; ++jj) {
#pragma unroll
    for (int r = 0; r < 4; ++r) {
      float v = psum[jj][r];
      v += __shfl_xor(v, 1);
      v += __shfl_xor(v, 2);
      v += __shfl_xor(v, 4);
      v += __shfl_xor(v, 8);
      if (cc == 0) sc_s[wc * NN + (wr * 4 + jj) * 16 + q * 4 + r] = v;
    }
  }
  __syncthreads();

  // ---- softmax over j (first 256 threads active; all 512 hit barriers) ----
  float score = 0.f, e = 0.f;
  if (t < NN) {
    score = sc_s[t] + sc_s[NN + t] + b2[0];
    if (t == i) score = -1.0e9f;
    red_s[t] = score;
  }
  __syncthreads();
  for (int s = 128; s > 0; s >>= 1) {
    if (t < s) red_s[t] = fmaxf(red_s[t], red_s[t + s]);
    __syncthreads();
  }
  const float m = red_s[0];
  __syncthreads();
  if (t < NN) { e = __expf(score - m); red_s[t] = e; }
  __syncthreads();
  for (int s = 128; s > 0; s >>= 1) {
    if (t < s) red_s[t] += red_s[t + s];
    __syncthreads();
  }
  if (t < NN) out[(size_t)bi * NN + t] = e / red_s[0];
}

extern "C" void kernel_launch(void* const* d_in, const int* in_sizes, int n_in,
                              void* d_out, int out_size, void* d_ws, size_t ws_size,
                              hipStream_t stream) {
  const float* X  = (const float*)d_in[0];
  const float* W1 = (const float*)d_in[1];
  const float* b1 = (const float*)d_in[2];
  const float* W2 = (const float*)d_in[3];
  const float* b2 = (const float*)d_in[4];
  float* out = (float*)d_out;

  float*     Sws  = (float*)d_ws;                                 // 1 MB
  float*     Tws  = Sws + (size_t)BB * NN * HH;                   // 1 MB
  _Float16*  Wf16 = (_Float16*)(Tws + (size_t)BB * NN * HH);      // 256 KB

  wcvt_kernel<<<256, 256, 0, stream>>>(W1, Wf16);
  precomp_st<<<BB * NN / RPB, 256, 0, stream>>>(X, W1, Sws, Tws);
  score_mfma<<<BB * NN, 512, 0, stream>>>(X, b1, W2, b2, Sws, Tws, Wf16, out);
}

// Round 4
// 296.770 us; speedup vs baseline: 4.6619x; 1.0357x over previous
//
#include <hip/hip_runtime.h>

#define BB 4
#define NN 256
#define DD 256
#define HH 256

typedef _Float16 half8 __attribute__((ext_vector_type(8)));
typedef __fp16   fp16x2 __attribute__((ext_vector_type(2)));
typedef float floatx4 __attribute__((ext_vector_type(4)));

// ---------- kernel 0: Wc/Wd (fp32) -> interleaved f16, chunk-major ----------
// Wf16 logical layout: [c][h][kkloc], c in [0,8), kkloc in [0,64).
// Global k index kk = c*64 + kkloc = 2*d + t; t=0 -> Wc[d][h], t=1 -> Wd[d][h].
__global__ __launch_bounds__(256) void wcvt_kernel(const float* __restrict__ W1,
                                                   _Float16* __restrict__ Wf16) {
  const int d = blockIdx.x;    // 0..255
  const int h = threadIdx.x;   // 0..255
  const float wc = W1[(size_t)(2 * DD + d) * HH + h];
  const float wd = W1[(size_t)(3 * DD + d) * HH + h];
  const int c  = d >> 5;
  const int dd = d & 31;
  _Float16* p = Wf16 + ((size_t)c * HH * 64 + (size_t)h * 64 + 2 * dd);
  p[0] = (_Float16)wc;   // RTN
  p[1] = (_Float16)wd;
}

// ---------- kernel 1: S[row,h] = X[row,:]*Wa, T[row,h] = X[row,:]*Wb ----------
#define RPB 8
__global__ __launch_bounds__(256) void precomp_st(const float* __restrict__ X,
                                                  const float* __restrict__ W1,
                                                  float* __restrict__ S,
                                                  float* __restrict__ T) {
  const int h    = threadIdx.x;
  const int row0 = blockIdx.x * RPB;       // global row = b*N + i
  __shared__ float xr[RPB][DD];
#pragma unroll
  for (int r = 0; r < RPB; ++r) xr[r][h] = X[(size_t)(row0 + r) * DD + h];
  __syncthreads();
  const float* __restrict__ Wa = W1;
  const float* __restrict__ Wb = W1 + (size_t)DD * HH;
  float sa[RPB], sb[RPB];
#pragma unroll
  for (int r = 0; r < RPB; ++r) { sa[r] = 0.f; sb[r] = 0.f; }
  for (int d = 0; d < DD; ++d) {
    const float wa = Wa[(size_t)d * HH + h];
    const float wb = Wb[(size_t)d * HH + h];
#pragma unroll
    for (int r = 0; r < RPB; ++r) {
      const float x = xr[r][d];            // LDS broadcast (free)
      sa[r] = fmaf(x, wa, sa[r]);
      sb[r] = fmaf(x, wb, sb[r]);
    }
  }
#pragma unroll
  for (int r = 0; r < RPB; ++r) {
    S[(size_t)(row0 + r) * HH + h] = sa[r];
    T[(size_t)(row0 + r) * HH + h] = sb[r];
  }
}

// ---------- kernel 2: MFMA pair-scores + softmax, one block per (b,i) ----------
// 1024 threads = 16 waves, wave (wr,wc): wr=wid&3 (j), wc=wid>>2 (h).
// Each wave: 4 j-tiles x 4 h-tiles -> acc[4][4] floatx4 = 64 VGPRs (no spill).
__global__ __launch_bounds__(1024) void score_mfma(
    const float* __restrict__ X,  const float* __restrict__ b1,
    const float* __restrict__ W2, const float* __restrict__ b2,
    const float* __restrict__ S,  const float* __restrict__ T,
    const _Float16* __restrict__ Wf16, float* __restrict__ out) {

  const int bi   = blockIdx.x;
  const int b    = bi >> 8;
  const int i    = bi & 255;
  const int t    = threadIdx.x;
  const int lane = t & 63;
  const int wid  = t >> 6;        // 0..15
  const int wr   = wid & 3;       // j-group
  const int wc   = wid >> 2;      // h-group 0..3
  const int q    = lane >> 4;     // 0..3
  const int cc   = lane & 15;     // 0..15

  __shared__ __align__(16) float    xi_s[DD];
  __shared__ __align__(16) _Float16 B_s[HH][72];   // padded rows: 144 B
  __shared__ float pre_s[HH];
  __shared__ float w2_s[HH];
  __shared__ float sc_s[4 * NN];
  __shared__ float red_s[NN];

  if (t < 256) {
    xi_s[t]  = X[(size_t)bi * DD + t];
    pre_s[t] = S[(size_t)bi * HH + t] + b1[t];
    w2_s[t]  = W2[t];
  }

  const float* __restrict__ Xb = X + (size_t)b * NN * DD;
  const float* __restrict__ Tb = T + (size_t)b * NN * HH;

  // per-wave constant index components (int offsets keep base in SGPRs)
  int xrow_off[4];                 // element offset of row j for each jj
#pragma unroll
  for (int jj = 0; jj < 4; ++jj)
    xrow_off[jj] = ((wr * 4 + jj) * 16 + cc) * DD;

  floatx4 acc[4][4];
#pragma unroll
  for (int jj = 0; jj < 4; ++jj)
#pragma unroll
    for (int hh = 0; hh < 4; ++hh) acc[jj][hh] = (floatx4)0.f;

  // B-chunk staging: 32 KB/chunk, 1024 threads x 32 B.
  const int srow = t >> 2;         // 0..255
  const int sq   = t & 3;          // 0..3
  const uint4* __restrict__ wsrc = (const uint4*)Wf16;   // chunk c at idx c*2048
  const int sidx = srow * 8 + sq * 2;
  uint4 bpre[2];
#pragma unroll
  for (int u = 0; u < 2; ++u) bpre[u] = wsrc[sidx + u];

  for (int ch = 0; ch < 8; ++ch) {
    __syncthreads();                       // previous chunk's reads done
    {
      uint4* bdst = (uint4*)&B_s[srow][sq * 16];
#pragma unroll
      for (int u = 0; u < 2; ++u) bdst[u] = bpre[u];
    }
    if (ch < 7) {
#pragma unroll
      for (int u = 0; u < 2; ++u) bpre[u] = wsrc[(ch + 1) * 2048 + sidx + u];
    }
    __syncthreads();                       // B_s ready

#pragma unroll
    for (int ksl = 0; ksl < 2; ++ksl) {
      const int ks    = ch * 2 + ksl;      // K-step 0..15 (K=32 each)
      const int dbase = ks * 16 + q * 4;   // this lane's 4 d's
      const float4 xiv = *(const float4*)&xi_s[dbase];

      half8 bfrag[4];
#pragma unroll
      for (int hh = 0; hh < 4; ++hh) {
        const int hr = (wc * 4 + hh) * 16 + cc;          // B row n
        bfrag[hh] = *(const half8*)&B_s[hr][ksl * 32 + q * 8];
      }

#pragma unroll
      for (int jj = 0; jj < 4; ++jj) {
        const float4 xj = *(const float4*)(Xb + xrow_off[jj] + dbase);
        union { half8 v; fp16x2 h2[4]; } af;
        af.h2[0] = __builtin_amdgcn_cvt_pkrtz(fabsf(xiv.x - xj.x), xiv.x * xj.x);
        af.h2[1] = __builtin_amdgcn_cvt_pkrtz(fabsf(xiv.y - xj.y), xiv.y * xj.y);
        af.h2[2] = __builtin_amdgcn_cvt_pkrtz(fabsf(xiv.z - xj.z), xiv.z * xj.z);
        af.h2[3] = __builtin_amdgcn_cvt_pkrtz(fabsf(xiv.w - xj.w), xiv.w * xj.w);
#pragma unroll
        for (int hh = 0; hh < 4; ++hh)
          acc[jj][hh] = __builtin_amdgcn_mfma_f32_16x16x32_f16(af.v, bfrag[hh],
                                                               acc[jj][hh], 0, 0, 0);
      }
    }
  }

  // ---- epilogue: add S/T/b1, silu, dot w2, reduce over this wave's 64 h ----
  float psum[4][4];
#pragma unroll
  for (int jj = 0; jj < 4; ++jj)
#pragma unroll
    for (int r = 0; r < 4; ++r) psum[jj][r] = 0.f;

#pragma unroll
  for (int hh = 0; hh < 4; ++hh) {
    const int h = (wc * 4 + hh) * 16 + cc;
    const float w2v = w2_s[h];
    const float pv  = pre_s[h];
#pragma unroll
    for (int jj = 0; jj < 4; ++jj) {
#pragma unroll
      for (int r = 0; r < 4; ++r) {
        const int j = (wr * 4 + jj) * 16 + q * 4 + r;    // C/D row = quad*4+reg
        const float tv = Tb[(size_t)j * HH + h];
        const float hv = acc[jj][hh][r] + pv + tv;
        const float sv = hv * __frcp_rn(1.f + __expf(-hv));  // silu
        psum[jj][r] = fmaf(sv, w2v, psum[jj][r]);
      }
    }
  }

  // reduce over the 16 h-columns (lane bits 0..3), lane cc==0 writes
#pragma unroll
  for (int jj = 0; jj < 4; ++jj) {
#pragma unroll
    for (int r = 0; r < 4; ++r) {
      float v = psum[jj][r];
      v += __shfl_xor(v, 1);
      v += __shfl_xor(v, 2);
      v += __shfl_xor(v, 4);
      v += __shfl_xor(v, 8);
      if (cc == 0) sc_s[wc * NN + (wr * 4 + jj) * 16 + q * 4 + r] = v;
    }
  }
  __syncthreads();

  // ---- softmax over j (first 256 threads active; all hit barriers) ----
  float score = 0.f, e = 0.f;
  if (t < NN) {
    score = sc_s[t] + sc_s[NN + t] + sc_s[2 * NN + t] + sc_s[3 * NN + t] + b2[0];
    if (t == i) score = -1.0e9f;
    red_s[t] = score;
  }
  __syncthreads();
  for (int s = 128; s > 0; s >>= 1) {
    if (t < s) red_s[t] = fmaxf(red_s[t], red_s[t + s]);
    __syncthreads();
  }
  const float m = red_s[0];
  __syncthreads();
  if (t < NN) { e = __expf(score - m); red_s[t] = e; }
  __syncthreads();
  for (int s = 128; s > 0; s >>= 1) {
    if (t < s) red_s[t] += red_s[t + s];
    __syncthreads();
  }
  if (t < NN) out[(size_t)bi * NN + t] = e / red_s[0];
}

extern "C" void kernel_launch(void* const* d_in, const int* in_sizes, int n_in,
                              void* d_out, int out_size, void* d_ws, size_t ws_size,
                              hipStream_t stream) {
  const float* X  = (const float*)d_in[0];
  const float* W1 = (const float*)d_in[1];
  const float* b1 = (const float*)d_in[2];
  const float* W2 = (const float*)d_in[3];
  const float* b2 = (const float*)d_in[4];
  float* out = (float*)d_out;

  float*     Sws  = (float*)d_ws;                                 // 1 MB
  float*     Tws  = Sws + (size_t)BB * NN * HH;                   // 1 MB
  _Float16*  Wf16 = (_Float16*)(Tws + (size_t)BB * NN * HH);      // 256 KB

  wcvt_kernel<<<256, 256, 0, stream>>>(W1, Wf16);
  precomp_st<<<BB * NN / RPB, 256, 0, stream>>>(X, W1, Sws, Tws);
  score_mfma<<<BB * NN, 1024, 0, stream>>>(X, b1, W2, b2, Sws, Tws, Wf16, out);
}